// Round 8
// baseline (635.947 us; speedup 1.0000x reference)
//
#include <hip/hip_runtime.h>
#include <hip/hip_bf16.h>
#include <math.h>

#define D 64
#define NEG_GAT 0.2f
#define NEG_OUT 0.01f
#define CHUNK 256

// ---- degree init/count (rp doubles as count -> start -> end cursor) ----
__global__ void k_init(int* __restrict__ rp, int N) {
    int n = blockIdx.x * blockDim.x + threadIdx.x;
    if (n < N) rp[n] = 1;   // self-loop
}

__global__ void k_count(const int* __restrict__ dstI, int* __restrict__ rp, int E) {
    int i = blockIdx.x * blockDim.x + threadIdx.x;
    if (i < E) atomicAdd(&rp[dstI[i]], 1);
}

// ---- node projection h = emb[x] @ W, attention logits ----
__global__ void k_node(const int* __restrict__ x,
                       const float* __restrict__ emb,
                       const float* __restrict__ W,
                       const float* __restrict__ att_src,
                       const float* __restrict__ att_dst,
                       float* __restrict__ h,
                       float* __restrict__ a_src, float* __restrict__ a_dst,
                       int N)
{
    __shared__ float Wl[D * D];
    for (int i = threadIdx.x; i < D * D; i += blockDim.x) Wl[i] = W[i];
    __syncthreads();

    const int lane = threadIdx.x & 63;
    const int n = blockIdx.x * 4 + (threadIdx.x >> 6);
    if (n >= N) return;

    const float* er = emb + (long long)x[n] * D;
    float hc = 0.0f;
#pragma unroll
    for (int d = 0; d < D; ++d)
        hc = fmaf(er[d], Wl[d * D + lane], hc);

    h[(long long)n * D + lane] = hc;

    float vs = hc * att_src[lane];
    float vd = hc * att_dst[lane];
#pragma unroll
    for (int o = 32; o >= 1; o >>= 1) {
        vs += __shfl_xor(vs, o);
        vd += __shfl_xor(vd, o);
    }
    if (lane == 0) { a_src[n] = vs; a_dst[n] = vd; }
}

// ---- exclusive scan of counts -> row starts (3 steps) ----
__global__ void k_scan1(const int* __restrict__ rp, int* __restrict__ partial, int N) {
    __shared__ int sm[CHUNK];
    int n = blockIdx.x * CHUNK + threadIdx.x;
    sm[threadIdx.x] = (n < N) ? rp[n] : 0;
    __syncthreads();
    for (int off = CHUNK / 2; off > 0; off >>= 1) {
        if (threadIdx.x < off) sm[threadIdx.x] += sm[threadIdx.x + off];
        __syncthreads();
    }
    if (threadIdx.x == 0) partial[blockIdx.x] = sm[0];
}

__global__ void k_scan2(int* __restrict__ partial, int NC) {
    __shared__ int sm[512];
    int t = threadIdx.x;
    int v = (t < NC) ? partial[t] : 0;
    sm[t] = v;
    __syncthreads();
    for (int off = 1; off < 512; off <<= 1) {
        int xv = (t >= off) ? sm[t - off] : 0;
        __syncthreads();
        sm[t] += xv;
        __syncthreads();
    }
    if (t < NC) partial[t] = sm[t] - v;   // exclusive
}

__global__ void k_scan3(int* __restrict__ rp, const int* __restrict__ partial, int N) {
    __shared__ int sm[CHUNK];
    int b = blockIdx.x, t = threadIdx.x;
    int n = b * CHUNK + t;
    int v = (n < N) ? rp[n] : 0;
    sm[t] = v;
    __syncthreads();
    for (int off = 1; off < CHUNK; off <<= 1) {
        int xv = (t >= off) ? sm[t - off] : 0;
        __syncthreads();
        sm[t] += xv;
        __syncthreads();
    }
    if (n < N) rp[n] = partial[b] + sm[t] - v;   // exclusive start
}

// ---- placement: perm[pos] = edge id (i>=E encodes self-loop of node i-E) ----
__global__ void k_place(const int* __restrict__ dstI, int* __restrict__ rp,
                        int* __restrict__ perm, int E, int N) {
    int i = blockIdx.x * blockDim.x + threadIdx.x;
    if (i >= E + N) return;
    int dn = (i < E) ? dstI[i] : (i - E);
    int pos = atomicAdd(&rp[dn], 1);
    perm[pos] = i;
}

// ---- per-dst softmax + aggregation (1 wave / node) ----
__global__ void k_agg(const int* __restrict__ srcI,
                      const int* __restrict__ rp,   // rp[n] = end of row n
                      const int* __restrict__ perm,
                      const float* __restrict__ a_src,
                      const float* __restrict__ a_dst,
                      const float* __restrict__ h,
                      const float* __restrict__ bias,
                      float* __restrict__ out,
                      float* __restrict__ alpha_out,
                      int E, int N)
{
    const int lane = threadIdx.x & 63;
    const int n = blockIdx.x * 4 + (threadIdx.x >> 6);
    if (n >= N) return;

    const int base = (n == 0) ? 0 : rp[n - 1];
    const int deg  = rp[n] - base;
    const float adn = a_dst[n];

    // pass 1: segment max (edge-parallel across lanes)
    float mx = -1e30f;
    for (int j = lane; j < deg; j += 64) {
        int eid = perm[base + j];
        int sn = (eid < E) ? srcI[eid] : n;
        float lg = a_src[sn] + adn;
        lg = lg > 0.0f ? lg : NEG_GAT * lg;
        mx = fmaxf(mx, lg);
    }
#pragma unroll
    for (int o = 32; o >= 1; o >>= 1) mx = fmaxf(mx, __shfl_xor(mx, o));

    // pass 2: sum of exp
    float se = 0.0f;
    for (int j = lane; j < deg; j += 64) {
        int eid = perm[base + j];
        int sn = (eid < E) ? srcI[eid] : n;
        float lg = a_src[sn] + adn;
        lg = lg > 0.0f ? lg : NEG_GAT * lg;
        se += __expf(lg - mx);
    }
#pragma unroll
    for (int o = 32; o >= 1; o >>= 1) se += __shfl_xor(se, o);
    const float inv = 1.0f / (se + 1e-16f);

    // pass 3: serial over edges, channel-parallel accumulate
    float acc = 0.0f;
    for (int j = 0; j < deg; ++j) {
        int eid = perm[base + j];
        int sn = (eid < E) ? srcI[eid] : n;
        float lg = a_src[sn] + adn;
        lg = lg > 0.0f ? lg : NEG_GAT * lg;
        float al = __expf(lg - mx) * inv;
        acc = fmaf(al, h[(long long)sn * D + lane], acc);
        if (lane == 0) alpha_out[eid] = al;
    }

    float v = acc + bias[lane];
    v = v > 0.0f ? v : NEG_OUT * v;
    out[(long long)n * D + lane] = v;
}

extern "C" void kernel_launch(void* const* d_in, const int* in_sizes, int n_in,
                              void* d_out, int out_size, void* d_ws, size_t ws_size,
                              hipStream_t stream)
{
    const int* x          = (const int*)d_in[0];
    const int* ei         = (const int*)d_in[1];
    const float* emb      = (const float*)d_in[2];
    const float* W        = (const float*)d_in[3];
    const float* att_src  = (const float*)d_in[4];
    const float* att_dst  = (const float*)d_in[5];
    const float* bias     = (const float*)d_in[6];

    const int N = in_sizes[0];
    const int E = in_sizes[1] / 2;
    const int* srcI = ei;       // edge_index[0]
    const int* dstI = ei + E;   // edge_index[1]
    const int NC = (N + CHUNK - 1) / CHUNK;

    char* p = (char*)d_ws;
    size_t off = 0;
    auto take = [&](size_t bytes) {
        char* q = p + off;
        off += (bytes + 15) & ~size_t(15);
        return q;
    };
    int* partial   = (int*)take((size_t)NC * 4);
    int* rp        = (int*)take((size_t)N * 4);
    float* a_src_b = (float*)take((size_t)N * 4);
    float* a_dst_b = (float*)take((size_t)N * 4);
    int* perm      = (int*)take((size_t)(E + N) * 4);
    float* h       = (float*)take((size_t)N * D * 4);   // total ~33.6 MB (fits: round-7 beacon confirmed)

    float* out       = (float*)d_out;                    // f32 output (round-7 beacon evidence)
    float* alpha_out = out + (long long)N * D;

    k_init <<<(N + 255) / 256, 256, 0, stream>>>(rp, N);
    k_count<<<(E + 255) / 256, 256, 0, stream>>>(dstI, rp, E);
    k_node <<<(N + 3) / 4, 256, 0, stream>>>(x, emb, W, att_src, att_dst,
                                             h, a_src_b, a_dst_b, N);
    k_scan1<<<NC, CHUNK, 0, stream>>>(rp, partial, N);
    k_scan2<<<1, 512, 0, stream>>>(partial, NC);
    k_scan3<<<NC, CHUNK, 0, stream>>>(rp, partial, N);
    k_place<<<(E + N + 255) / 256, 256, 0, stream>>>(dstI, rp, perm, E, N);
    k_agg  <<<(N + 3) / 4, 256, 0, stream>>>(srcI, rp, perm, a_src_b, a_dst_b,
                                             h, bias, out, alpha_out, E, N);
}

// Round 9
// 443.503 us; speedup vs baseline: 1.4339x; 1.4339x over previous
//
#include <hip/hip_runtime.h>
#include <hip/hip_bf16.h>
#include <math.h>

#define D 64
#define NEG_GAT 0.2f
#define NEG_OUT 0.01f
#define CHUNK 256
#define MAXD 256   // LDS edge-cache capacity per node (P(deg>256)~0 for E/N=16; fallback below)

// ---- degree init/count (rp doubles as count -> start -> end cursor) ----
__global__ void k_init(int* __restrict__ rp, int N) {
    int n = blockIdx.x * blockDim.x + threadIdx.x;
    if (n < N) rp[n] = 1;   // self-loop
}

__global__ void k_count(const int* __restrict__ dstI, int* __restrict__ rp, int E) {
    int i = blockIdx.x * blockDim.x + threadIdx.x;
    if (i < E) atomicAdd(&rp[dstI[i]], 1);
}

// ---- node projection h = emb[x] @ W, attention logits ----
__global__ void k_node(const int* __restrict__ x,
                       const float* __restrict__ emb,
                       const float* __restrict__ W,
                       const float* __restrict__ att_src,
                       const float* __restrict__ att_dst,
                       float* __restrict__ h,
                       float* __restrict__ a_src, float* __restrict__ a_dst,
                       int N)
{
    __shared__ float Wl[D * D];
    for (int i = threadIdx.x; i < D * D; i += blockDim.x) Wl[i] = W[i];
    __syncthreads();

    const int lane = threadIdx.x & 63;
    const int n = blockIdx.x * 4 + (threadIdx.x >> 6);
    if (n >= N) return;

    const float* er = emb + (long long)x[n] * D;
    float hc = 0.0f;
#pragma unroll
    for (int d = 0; d < D; ++d)
        hc = fmaf(er[d], Wl[d * D + lane], hc);

    h[(long long)n * D + lane] = hc;

    float vs = hc * att_src[lane];
    float vd = hc * att_dst[lane];
#pragma unroll
    for (int o = 32; o >= 1; o >>= 1) {
        vs += __shfl_xor(vs, o);
        vd += __shfl_xor(vd, o);
    }
    if (lane == 0) { a_src[n] = vs; a_dst[n] = vd; }
}

// ---- exclusive scan of counts -> row starts (3 steps) ----
__global__ void k_scan1(const int* __restrict__ rp, int* __restrict__ partial, int N) {
    __shared__ int sm[CHUNK];
    int n = blockIdx.x * CHUNK + threadIdx.x;
    sm[threadIdx.x] = (n < N) ? rp[n] : 0;
    __syncthreads();
    for (int off = CHUNK / 2; off > 0; off >>= 1) {
        if (threadIdx.x < off) sm[threadIdx.x] += sm[threadIdx.x + off];
        __syncthreads();
    }
    if (threadIdx.x == 0) partial[blockIdx.x] = sm[0];
}

__global__ void k_scan2(int* __restrict__ partial, int NC) {
    __shared__ int sm[512];
    int t = threadIdx.x;
    int v = (t < NC) ? partial[t] : 0;
    sm[t] = v;
    __syncthreads();
    for (int off = 1; off < 512; off <<= 1) {
        int xv = (t >= off) ? sm[t - off] : 0;
        __syncthreads();
        sm[t] += xv;
        __syncthreads();
    }
    if (t < NC) partial[t] = sm[t] - v;   // exclusive
}

__global__ void k_scan3(int* __restrict__ rp, const int* __restrict__ partial, int N) {
    __shared__ int sm[CHUNK];
    int b = blockIdx.x, t = threadIdx.x;
    int n = b * CHUNK + t;
    int v = (n < N) ? rp[n] : 0;
    sm[t] = v;
    __syncthreads();
    for (int off = 1; off < CHUNK; off <<= 1) {
        int xv = (t >= off) ? sm[t - off] : 0;
        __syncthreads();
        sm[t] += xv;
        __syncthreads();
    }
    if (n < N) rp[n] = partial[b] + sm[t] - v;   // exclusive start
}

// ---- placement: perm[pos] = edge id (i>=E encodes self-loop of node i-E) ----
__global__ void k_place(const int* __restrict__ dstI, int* __restrict__ rp,
                        int* __restrict__ perm, int E, int N) {
    int i = blockIdx.x * blockDim.x + threadIdx.x;
    if (i >= E + N) return;
    int dn = (i < E) ? dstI[i] : (i - E);
    int pos = atomicAdd(&rp[dn], 1);
    perm[pos] = i;
}

// ---- per-dst softmax + aggregation (1 wave / node, LDS edge cache) ----
__global__ void k_agg(const int* __restrict__ srcI,
                      const int* __restrict__ rp,   // rp[n] = end of row n
                      const int* __restrict__ perm,
                      const float* __restrict__ a_src,
                      const float* __restrict__ a_dst,
                      const float* __restrict__ h,
                      const float* __restrict__ bias,
                      float* __restrict__ out,
                      float* __restrict__ alpha_out,
                      int E, int N)
{
    __shared__ int   sn_s[4][MAXD];
    __shared__ int   eid_s[4][MAXD];
    __shared__ float al_s[4][MAXD];

    const int lane = threadIdx.x & 63;
    const int w    = threadIdx.x >> 6;
    const int n = blockIdx.x * 4 + w;
    if (n >= N) return;

    const int base = (n == 0) ? 0 : rp[n - 1];
    const int deg  = rp[n] - base;
    const float adn = a_dst[n];

    if (deg <= MAXD) {
        // pass A: gather edge meta once, compute logit, cache in LDS, track max
        float mx = -1e30f;
        for (int j = lane; j < deg; j += 64) {
            int eid = perm[base + j];
            int sn = (eid < E) ? srcI[eid] : n;
            sn_s[w][j]  = sn;
            eid_s[w][j] = eid;
            float lg = a_src[sn] + adn;
            lg = lg > 0.0f ? lg : NEG_GAT * lg;
            al_s[w][j] = lg;
            mx = fmaxf(mx, lg);
        }
#pragma unroll
        for (int o = 32; o >= 1; o >>= 1) mx = fmaxf(mx, __shfl_xor(mx, o));

        // pass B: exp in place, sum
        float se = 0.0f;
        for (int j = lane; j < deg; j += 64) {
            float ex = __expf(al_s[w][j] - mx);
            al_s[w][j] = ex;
            se += ex;
        }
#pragma unroll
        for (int o = 32; o >= 1; o >>= 1) se += __shfl_xor(se, o);
        const float inv = 1.0f / (se + 1e-16f);

        // pass C: 4 edge-slots x 16 float4-channels; normalization folded at end
        const int e = lane >> 4;    // edge slot 0..3
        const int c = lane & 15;    // float4 index in row (channels 4c..4c+3)
        float4 acc = make_float4(0.f, 0.f, 0.f, 0.f);
#pragma unroll 2
        for (int j = e; j < deg; j += 4) {
            const float al = al_s[w][j];
            const float4 hv =
                reinterpret_cast<const float4*>(h + (long long)sn_s[w][j] * D)[c];
            acc.x = fmaf(al, hv.x, acc.x);
            acc.y = fmaf(al, hv.y, acc.y);
            acc.z = fmaf(al, hv.z, acc.z);
            acc.w = fmaf(al, hv.w, acc.w);
        }
#pragma unroll
        for (int o = 16; o <= 32; o <<= 1) {
            acc.x += __shfl_xor(acc.x, o);
            acc.y += __shfl_xor(acc.y, o);
            acc.z += __shfl_xor(acc.z, o);
            acc.w += __shfl_xor(acc.w, o);
        }

        // pass D: alpha writes, edge-parallel
        for (int j = lane; j < deg; j += 64)
            alpha_out[eid_s[w][j]] = al_s[w][j] * inv;

        if (lane < 16) {
            const float4 b4 = reinterpret_cast<const float4*>(bias)[c];
            float4 v;
            v.x = acc.x * inv + b4.x;
            v.y = acc.y * inv + b4.y;
            v.z = acc.z * inv + b4.z;
            v.w = acc.w * inv + b4.w;
            v.x = v.x > 0.0f ? v.x : NEG_OUT * v.x;
            v.y = v.y > 0.0f ? v.y : NEG_OUT * v.y;
            v.z = v.z > 0.0f ? v.z : NEG_OUT * v.z;
            v.w = v.w > 0.0f ? v.w : NEG_OUT * v.w;
            reinterpret_cast<float4*>(out + (long long)n * D)[c] = v;
        }
    } else {
        // fallback: 3-pass, no LDS (rare)
        float mx = -1e30f;
        for (int j = lane; j < deg; j += 64) {
            int eid = perm[base + j];
            int sn = (eid < E) ? srcI[eid] : n;
            float lg = a_src[sn] + adn;
            lg = lg > 0.0f ? lg : NEG_GAT * lg;
            mx = fmaxf(mx, lg);
        }
#pragma unroll
        for (int o = 32; o >= 1; o >>= 1) mx = fmaxf(mx, __shfl_xor(mx, o));

        float se = 0.0f;
        for (int j = lane; j < deg; j += 64) {
            int eid = perm[base + j];
            int sn = (eid < E) ? srcI[eid] : n;
            float lg = a_src[sn] + adn;
            lg = lg > 0.0f ? lg : NEG_GAT * lg;
            se += __expf(lg - mx);
        }
#pragma unroll
        for (int o = 32; o >= 1; o >>= 1) se += __shfl_xor(se, o);
        const float inv = 1.0f / (se + 1e-16f);

        float acc = 0.0f;
        for (int j = 0; j < deg; ++j) {
            int eid = perm[base + j];
            int sn = (eid < E) ? srcI[eid] : n;
            float lg = a_src[sn] + adn;
            lg = lg > 0.0f ? lg : NEG_GAT * lg;
            float al = __expf(lg - mx) * inv;
            acc = fmaf(al, h[(long long)sn * D + lane], acc);
            if (lane == 0) alpha_out[eid] = al;
        }
        float v = acc + bias[lane];
        v = v > 0.0f ? v : NEG_OUT * v;
        out[(long long)n * D + lane] = v;
    }
}

extern "C" void kernel_launch(void* const* d_in, const int* in_sizes, int n_in,
                              void* d_out, int out_size, void* d_ws, size_t ws_size,
                              hipStream_t stream)
{
    const int* x          = (const int*)d_in[0];
    const int* ei         = (const int*)d_in[1];
    const float* emb      = (const float*)d_in[2];
    const float* W        = (const float*)d_in[3];
    const float* att_src  = (const float*)d_in[4];
    const float* att_dst  = (const float*)d_in[5];
    const float* bias     = (const float*)d_in[6];

    const int N = in_sizes[0];
    const int E = in_sizes[1] / 2;
    const int* srcI = ei;       // edge_index[0]
    const int* dstI = ei + E;   // edge_index[1]
    const int NC = (N + CHUNK - 1) / CHUNK;

    char* p = (char*)d_ws;
    size_t off = 0;
    auto take = [&](size_t bytes) {
        char* q = p + off;
        off += (bytes + 15) & ~size_t(15);
        return q;
    };
    int* partial   = (int*)take((size_t)NC * 4);
    int* rp        = (int*)take((size_t)N * 4);
    float* a_src_b = (float*)take((size_t)N * 4);
    float* a_dst_b = (float*)take((size_t)N * 4);
    int* perm      = (int*)take((size_t)(E + N) * 4);
    float* h       = (float*)take((size_t)N * D * 4);   // ~33.6 MB total, fits (r7 beacon)

    float* out       = (float*)d_out;
    float* alpha_out = out + (long long)N * D;

    k_init <<<(N + 255) / 256, 256, 0, stream>>>(rp, N);
    k_count<<<(E + 255) / 256, 256, 0, stream>>>(dstI, rp, E);
    k_node <<<(N + 3) / 4, 256, 0, stream>>>(x, emb, W, att_src, att_dst,
                                             h, a_src_b, a_dst_b, N);
    k_scan1<<<NC, CHUNK, 0, stream>>>(rp, partial, N);
    k_scan2<<<1, 512, 0, stream>>>(partial, NC);
    k_scan3<<<NC, CHUNK, 0, stream>>>(rp, partial, N);
    k_place<<<(E + N + 255) / 256, 256, 0, stream>>>(dstI, rp, perm, E, N);
    k_agg  <<<(N + 3) / 4, 256, 0, stream>>>(srcI, rp, perm, a_src_b, a_dst_b,
                                             h, bias, out, alpha_out, E, N);
}

// Round 10
// 413.523 us; speedup vs baseline: 1.5379x; 1.0725x over previous
//
#include <hip/hip_runtime.h>
#include <hip/hip_bf16.h>
#include <math.h>

#define D 64
#define NEG_GAT 0.2f
#define NEG_OUT 0.01f
#define CHUNK 256
#define MAXD 256   // LDS edge-cache capacity per node; fallback below for larger degrees

// ---- degree init/count (rp doubles as count -> start -> end cursor) ----
__global__ void k_init(int* __restrict__ rp, int N) {
    int n = blockIdx.x * blockDim.x + threadIdx.x;
    if (n < N) rp[n] = 1;   // self-loop
}

__global__ void k_count(const int* __restrict__ dstI, int* __restrict__ rp, int E) {
    int i = blockIdx.x * blockDim.x + threadIdx.x;
    if (i < E) atomicAdd(&rp[dstI[i]], 1);
}

// ---- node projection h = emb[x] @ W, attention logits ----
__global__ void k_node(const int* __restrict__ x,
                       const float* __restrict__ emb,
                       const float* __restrict__ W,
                       const float* __restrict__ att_src,
                       const float* __restrict__ att_dst,
                       float* __restrict__ h,
                       float* __restrict__ a_src, float* __restrict__ a_dst,
                       int N)
{
    __shared__ float Wl[D * D];
    for (int i = threadIdx.x; i < D * D; i += blockDim.x) Wl[i] = W[i];
    __syncthreads();

    const int lane = threadIdx.x & 63;
    const int n = blockIdx.x * 4 + (threadIdx.x >> 6);
    if (n >= N) return;

    const float* er = emb + (long long)x[n] * D;
    float hc = 0.0f;
#pragma unroll
    for (int d = 0; d < D; ++d)
        hc = fmaf(er[d], Wl[d * D + lane], hc);

    h[(long long)n * D + lane] = hc;

    float vs = hc * att_src[lane];
    float vd = hc * att_dst[lane];
#pragma unroll
    for (int o = 32; o >= 1; o >>= 1) {
        vs += __shfl_xor(vs, o);
        vd += __shfl_xor(vd, o);
    }
    if (lane == 0) { a_src[n] = vs; a_dst[n] = vd; }
}

// ---- exclusive scan of counts -> row starts (3 steps) ----
__global__ void k_scan1(const int* __restrict__ rp, int* __restrict__ partial, int N) {
    __shared__ int sm[CHUNK];
    int n = blockIdx.x * CHUNK + threadIdx.x;
    sm[threadIdx.x] = (n < N) ? rp[n] : 0;
    __syncthreads();
    for (int off = CHUNK / 2; off > 0; off >>= 1) {
        if (threadIdx.x < off) sm[threadIdx.x] += sm[threadIdx.x + off];
        __syncthreads();
    }
    if (threadIdx.x == 0) partial[blockIdx.x] = sm[0];
}

__global__ void k_scan2(int* __restrict__ partial, int NC) {
    __shared__ int sm[512];
    int t = threadIdx.x;
    int v = (t < NC) ? partial[t] : 0;
    sm[t] = v;
    __syncthreads();
    for (int off = 1; off < 512; off <<= 1) {
        int xv = (t >= off) ? sm[t - off] : 0;
        __syncthreads();
        sm[t] += xv;
        __syncthreads();
    }
    if (t < NC) partial[t] = sm[t] - v;   // exclusive
}

__global__ void k_scan3(int* __restrict__ rp, const int* __restrict__ partial, int N) {
    __shared__ int sm[CHUNK];
    int b = blockIdx.x, t = threadIdx.x;
    int n = b * CHUNK + t;
    int v = (n < N) ? rp[n] : 0;
    sm[t] = v;
    __syncthreads();
    for (int off = 1; off < CHUNK; off <<= 1) {
        int xv = (t >= off) ? sm[t - off] : 0;
        __syncthreads();
        sm[t] += xv;
        __syncthreads();
    }
    if (n < N) rp[n] = partial[b] + sm[t] - v;   // exclusive start
}

// ---- placement: perm[pos] = SOURCE NODE of the edge (self-loop: n) ----
__global__ void k_place(const int* __restrict__ srcI, const int* __restrict__ dstI,
                        int* __restrict__ rp, int* __restrict__ perm, int E, int N) {
    int i = blockIdx.x * blockDim.x + threadIdx.x;
    if (i >= E + N) return;
    int dn, sn;
    if (i < E) { dn = dstI[i]; sn = srcI[i]; }
    else       { dn = i - E;   sn = dn; }
    int pos = atomicAdd(&rp[dn], 1);
    perm[pos] = sn;
}

// ---- per-dst softmax + aggregation (1 wave / node, LDS edge cache) ----
// Writes out; parks scale[n] = inv*exp(-mx) in alpha_out[E+n] (self-loop slot).
__global__ void k_agg(const int* __restrict__ rp,   // rp[n] = end of row n
                      const int* __restrict__ perm, // src node per CSR slot
                      const float* __restrict__ a_src,
                      const float* __restrict__ a_dst,
                      const float* __restrict__ h,
                      const float* __restrict__ bias,
                      float* __restrict__ out,
                      float* __restrict__ scale_slots,  // = alpha_out + E
                      int E, int N)
{
    __shared__ int   sn_s[4][MAXD];
    __shared__ float al_s[4][MAXD];

    const int lane = threadIdx.x & 63;
    const int w    = threadIdx.x >> 6;
    const int n = blockIdx.x * 4 + w;
    if (n >= N) return;

    const int base = (n == 0) ? 0 : rp[n - 1];
    const int deg  = rp[n] - base;
    const float adn = a_dst[n];

    if (deg <= MAXD) {
        // pass A: logits into LDS once, track max
        float mx = -1e30f;
        for (int j = lane; j < deg; j += 64) {
            int sn = perm[base + j];          // coalesced, no indirection
            sn_s[w][j] = sn;
            float lg = a_src[sn] + adn;
            lg = lg > 0.0f ? lg : NEG_GAT * lg;
            al_s[w][j] = lg;
            mx = fmaxf(mx, lg);
        }
#pragma unroll
        for (int o = 32; o >= 1; o >>= 1) mx = fmaxf(mx, __shfl_xor(mx, o));

        // pass B: exp in place, sum
        float se = 0.0f;
        for (int j = lane; j < deg; j += 64) {
            float ex = __expf(al_s[w][j] - mx);
            al_s[w][j] = ex;
            se += ex;
        }
#pragma unroll
        for (int o = 32; o >= 1; o >>= 1) se += __shfl_xor(se, o);
        const float inv = 1.0f / (se + 1e-16f);
        if (lane == 0) scale_slots[n] = inv * __expf(-mx);

        // pass C: 4 edge-slots x 16 float4-channels; normalize once at end
        const int e = lane >> 4;
        const int c = lane & 15;
        float4 acc = make_float4(0.f, 0.f, 0.f, 0.f);
#pragma unroll 2
        for (int j = e; j < deg; j += 4) {
            const float al = al_s[w][j];
            const float4 hv =
                reinterpret_cast<const float4*>(h + (long long)sn_s[w][j] * D)[c];
            acc.x = fmaf(al, hv.x, acc.x);
            acc.y = fmaf(al, hv.y, acc.y);
            acc.z = fmaf(al, hv.z, acc.z);
            acc.w = fmaf(al, hv.w, acc.w);
        }
#pragma unroll
        for (int o = 16; o <= 32; o <<= 1) {
            acc.x += __shfl_xor(acc.x, o);
            acc.y += __shfl_xor(acc.y, o);
            acc.z += __shfl_xor(acc.z, o);
            acc.w += __shfl_xor(acc.w, o);
        }

        if (lane < 16) {
            const float4 b4 = reinterpret_cast<const float4*>(bias)[c];
            float4 v;
            v.x = acc.x * inv + b4.x;
            v.y = acc.y * inv + b4.y;
            v.z = acc.z * inv + b4.z;
            v.w = acc.w * inv + b4.w;
            v.x = v.x > 0.0f ? v.x : NEG_OUT * v.x;
            v.y = v.y > 0.0f ? v.y : NEG_OUT * v.y;
            v.z = v.z > 0.0f ? v.z : NEG_OUT * v.z;
            v.w = v.w > 0.0f ? v.w : NEG_OUT * v.w;
            reinterpret_cast<float4*>(out + (long long)n * D)[c] = v;
        }
    } else {
        // fallback for deg > MAXD (statistically never; correctness-required)
        float mx = -1e30f;
        for (int j = lane; j < deg; j += 64) {
            int sn = perm[base + j];
            float lg = a_src[sn] + adn;
            lg = lg > 0.0f ? lg : NEG_GAT * lg;
            mx = fmaxf(mx, lg);
        }
#pragma unroll
        for (int o = 32; o >= 1; o >>= 1) mx = fmaxf(mx, __shfl_xor(mx, o));

        float se = 0.0f;
        for (int j = lane; j < deg; j += 64) {
            int sn = perm[base + j];
            float lg = a_src[sn] + adn;
            lg = lg > 0.0f ? lg : NEG_GAT * lg;
            se += __expf(lg - mx);
        }
#pragma unroll
        for (int o = 32; o >= 1; o >>= 1) se += __shfl_xor(se, o);
        const float inv = 1.0f / (se + 1e-16f);
        if (lane == 0) scale_slots[n] = inv * __expf(-mx);

        float acc = 0.0f;
        for (int j = 0; j < deg; ++j) {
            int sn = perm[base + j];
            float lg = a_src[sn] + adn;
            lg = lg > 0.0f ? lg : NEG_GAT * lg;
            float al = __expf(lg - mx) * inv;
            acc = fmaf(al, h[(long long)sn * D + lane], acc);
        }
        float v = acc + bias[lane];
        v = v > 0.0f ? v : NEG_OUT * v;
        out[(long long)n * D + lane] = v;
    }
}

// ---- alpha in edge order (coalesced writes); scale read from parked slots ----
__global__ void k_alphaE(const int* __restrict__ srcI, const int* __restrict__ dstI,
                         const float* __restrict__ a_src, const float* __restrict__ a_dst,
                         const float* __restrict__ scale_slots,
                         float* __restrict__ alpha_out, int E)
{
    int i = blockIdx.x * blockDim.x + threadIdx.x;
    if (i >= E) return;
    int sn = srcI[i], dn = dstI[i];
    float lg = a_src[sn] + a_dst[dn];
    lg = lg > 0.0f ? lg : NEG_GAT * lg;
    alpha_out[i] = __expf(lg) * scale_slots[dn];
}

// ---- self-loop alpha: overwrite parked scale with true alpha (per-thread RMW) ----
__global__ void k_alphaS(const float* __restrict__ a_src, const float* __restrict__ a_dst,
                         float* __restrict__ scale_slots, int N)
{
    int n = blockIdx.x * blockDim.x + threadIdx.x;
    if (n >= N) return;
    float lg = a_src[n] + a_dst[n];
    lg = lg > 0.0f ? lg : NEG_GAT * lg;
    scale_slots[n] = __expf(lg) * scale_slots[n];
}

extern "C" void kernel_launch(void* const* d_in, const int* in_sizes, int n_in,
                              void* d_out, int out_size, void* d_ws, size_t ws_size,
                              hipStream_t stream)
{
    const int* x          = (const int*)d_in[0];
    const int* ei         = (const int*)d_in[1];
    const float* emb      = (const float*)d_in[2];
    const float* W        = (const float*)d_in[3];
    const float* att_src  = (const float*)d_in[4];
    const float* att_dst  = (const float*)d_in[5];
    const float* bias     = (const float*)d_in[6];

    const int N = in_sizes[0];
    const int E = in_sizes[1] / 2;
    const int* srcI = ei;       // edge_index[0]
    const int* dstI = ei + E;   // edge_index[1]
    const int NC = (N + CHUNK - 1) / CHUNK;

    char* p = (char*)d_ws;
    size_t off = 0;
    auto take = [&](size_t bytes) {
        char* q = p + off;
        off += (bytes + 15) & ~size_t(15);
        return q;
    };
    int* partial   = (int*)take((size_t)NC * 4);
    int* rp        = (int*)take((size_t)N * 4);
    float* a_src_b = (float*)take((size_t)N * 4);
    float* a_dst_b = (float*)take((size_t)N * 4);
    int* perm      = (int*)take((size_t)(E + N) * 4);
    float* h       = (float*)take((size_t)N * D * 4);   // ~33.6 MB total (proven fit, r7 beacon)

    float* out         = (float*)d_out;
    float* alpha_out   = out + (long long)N * D;
    float* scale_slots = alpha_out + E;                 // self-loop alpha slots, reused as scale park

    k_init  <<<(N + 255) / 256, 256, 0, stream>>>(rp, N);
    k_count <<<(E + 255) / 256, 256, 0, stream>>>(dstI, rp, E);
    k_node  <<<(N + 3) / 4, 256, 0, stream>>>(x, emb, W, att_src, att_dst,
                                              h, a_src_b, a_dst_b, N);
    k_scan1 <<<NC, CHUNK, 0, stream>>>(rp, partial, N);
    k_scan2 <<<1, 512, 0, stream>>>(partial, NC);
    k_scan3 <<<NC, CHUNK, 0, stream>>>(rp, partial, N);
    k_place <<<(E + N + 255) / 256, 256, 0, stream>>>(srcI, dstI, rp, perm, E, N);
    k_agg   <<<(N + 3) / 4, 256, 0, stream>>>(rp, perm, a_src_b, a_dst_b,
                                              h, bias, out, scale_slots, E, N);
    k_alphaE<<<(E + 255) / 256, 256, 0, stream>>>(srcI, dstI, a_src_b, a_dst_b,
                                                  scale_slots, alpha_out, E);
    k_alphaS<<<(N + 255) / 256, 256, 0, stream>>>(a_src_b, a_dst_b, scale_slots, N);
}

// Round 12
// 384.074 us; speedup vs baseline: 1.6558x; 1.0767x over previous
//
#include <hip/hip_runtime.h>
#include <hip/hip_bf16.h>
#include <math.h>

#define D 64
#define NEG_GAT 0.2f
#define NEG_OUT 0.01f
#define CHUNK 256
#define MAXD 256   // LDS edge-cache capacity per node in k_agg; fallback below

typedef __hip_bfloat16 bf16;

// exact bf16->f32 from a packed u32 (low half = even element, high = odd)
__device__ __forceinline__ float bf_lo(unsigned u) { return __uint_as_float(u << 16); }
__device__ __forceinline__ float bf_hi(unsigned u) { return __uint_as_float(u & 0xffff0000u); }

// ---- degree init/count (rp doubles as count -> start -> end cursor) ----
__global__ void k_init(int* __restrict__ rp, int N) {
    int n = blockIdx.x * blockDim.x + threadIdx.x;
    if (n < N) rp[n] = 1;   // self-loop
}

__global__ void k_count(const int* __restrict__ dstI, int* __restrict__ rp, int E) {
    int i = blockIdx.x * blockDim.x + threadIdx.x;
    if (i < E) atomicAdd(&rp[dstI[i]], 1);
}

// ---- node projection h = emb[x] @ W (f32 math, bf16 store), attention logits ----
__global__ void k_node(const int* __restrict__ x,
                       const float* __restrict__ emb,
                       const float* __restrict__ W,
                       const float* __restrict__ att_src,
                       const float* __restrict__ att_dst,
                       bf16* __restrict__ hb,
                       float* __restrict__ a_src, float* __restrict__ a_dst,
                       int N)
{
    __shared__ float Wl[D * D];
    for (int i = threadIdx.x; i < D * D; i += blockDim.x) Wl[i] = W[i];
    __syncthreads();

    const int lane = threadIdx.x & 63;
    const int n = blockIdx.x * 4 + (threadIdx.x >> 6);
    if (n >= N) return;

    const float* er = emb + (long long)x[n] * D;
    float hc = 0.0f;
#pragma unroll
    for (int d = 0; d < D; ++d)
        hc = fmaf(er[d], Wl[d * D + lane], hc);

    hb[(long long)n * D + lane] = __float2bfloat16(hc);

    float vs = hc * att_src[lane];
    float vd = hc * att_dst[lane];
#pragma unroll
    for (int o = 32; o >= 1; o >>= 1) {
        vs += __shfl_xor(vs, o);
        vd += __shfl_xor(vd, o);
    }
    if (lane == 0) { a_src[n] = vs; a_dst[n] = vd; }
}

// ---- exclusive scan of counts -> row starts (3 steps) ----
__global__ void k_scan1(const int* __restrict__ rp, int* __restrict__ partial, int N) {
    __shared__ int sm[CHUNK];
    int n = blockIdx.x * CHUNK + threadIdx.x;
    sm[threadIdx.x] = (n < N) ? rp[n] : 0;
    __syncthreads();
    for (int off = CHUNK / 2; off > 0; off >>= 1) {
        if (threadIdx.x < off) sm[threadIdx.x] += sm[threadIdx.x + off];
        __syncthreads();
    }
    if (threadIdx.x == 0) partial[blockIdx.x] = sm[0];
}

__global__ void k_scan2(int* __restrict__ partial, int NC) {
    __shared__ int sm[512];
    int t = threadIdx.x;
    int v = (t < NC) ? partial[t] : 0;
    sm[t] = v;
    __syncthreads();
    for (int off = 1; off < 512; off <<= 1) {
        int xv = (t >= off) ? sm[t - off] : 0;
        __syncthreads();
        sm[t] += xv;
        __syncthreads();
    }
    if (t < NC) partial[t] = sm[t] - v;   // exclusive
}

__global__ void k_scan3(int* __restrict__ rp, const int* __restrict__ partial, int N) {
    __shared__ int sm[CHUNK];
    int b = blockIdx.x, t = threadIdx.x;
    int n = b * CHUNK + t;
    int v = (n < N) ? rp[n] : 0;
    sm[t] = v;
    __syncthreads();
    for (int off = 1; off < CHUNK; off <<= 1) {
        int xv = (t >= off) ? sm[t - off] : 0;
        __syncthreads();
        sm[t] += xv;
        __syncthreads();
    }
    if (n < N) rp[n] = partial[b] + sm[t] - v;   // exclusive start
}

// ---- placement: perm[pos] = SOURCE NODE of the edge (self-loop: n) ----
// (r10-proven direct scatter; bucketed two-phase variant regressed under
//  graph replay in r11 -- do not reintroduce without sole-change validation)
__global__ void k_place(const int* __restrict__ srcI, const int* __restrict__ dstI,
                        int* __restrict__ rp, int* __restrict__ perm, int E, int N) {
    int i = blockIdx.x * blockDim.x + threadIdx.x;
    if (i >= E + N) return;
    int dn, sn;
    if (i < E) { dn = dstI[i]; sn = srcI[i]; }
    else       { dn = i - E;   sn = dn; }
    int pos = atomicAdd(&rp[dn], 1);
    perm[pos] = sn;
}

// ---- per-dst softmax + aggregation (1 wave / node, LDS edge cache, bf16 h) ----
// Writes out; parks scale[n] = inv*exp(-mx) in alpha_out[E+n] (self-loop slot).
__global__ void k_agg(const int* __restrict__ rp,   // rp[n] = end of row n
                      const int* __restrict__ perm, // src node per CSR slot
                      const float* __restrict__ a_src,
                      const float* __restrict__ a_dst,
                      const bf16* __restrict__ hb,
                      const float* __restrict__ bias,
                      float* __restrict__ out,
                      float* __restrict__ scale_slots,  // = alpha_out + E
                      int E, int N)
{
    __shared__ int   sn_s[4][MAXD];
    __shared__ float al_s[4][MAXD];

    const int lane = threadIdx.x & 63;
    const int w    = threadIdx.x >> 6;
    const int n = blockIdx.x * 4 + w;
    if (n >= N) return;

    const int base = (n == 0) ? 0 : rp[n - 1];
    const int deg  = rp[n] - base;
    const float adn = a_dst[n];

    if (deg <= MAXD) {
        // pass A: logits into LDS once, track max
        float mx = -1e30f;
        for (int j = lane; j < deg; j += 64) {
            int sn = perm[base + j];          // coalesced
            sn_s[w][j] = sn;
            float lg = a_src[sn] + adn;
            lg = lg > 0.0f ? lg : NEG_GAT * lg;
            al_s[w][j] = lg;
            mx = fmaxf(mx, lg);
        }
#pragma unroll
        for (int o = 32; o >= 1; o >>= 1) mx = fmaxf(mx, __shfl_xor(mx, o));

        // pass B: exp in place, sum
        float se = 0.0f;
        for (int j = lane; j < deg; j += 64) {
            float ex = __expf(al_s[w][j] - mx);
            al_s[w][j] = ex;
            se += ex;
        }
#pragma unroll
        for (int o = 32; o >= 1; o >>= 1) se += __shfl_xor(se, o);
        const float inv = 1.0f / (se + 1e-16f);
        if (lane == 0) scale_slots[n] = inv * __expf(-mx);

        // pass C: 8 edge-slots x 8 bf16x8 chunks (16B loads, 8 in flight/wave)
        const int e = lane >> 3;    // edge slot 0..7
        const int c = lane & 7;     // 16B chunk of the 128B row
        float acc[8] = {0.f, 0.f, 0.f, 0.f, 0.f, 0.f, 0.f, 0.f};
#pragma unroll 2
        for (int j = e; j < deg; j += 8) {
            const float al = al_s[w][j];
            const uint4 u =
                reinterpret_cast<const uint4*>(hb + (long long)sn_s[w][j] * D)[c];
            acc[0] = fmaf(al, bf_lo(u.x), acc[0]);
            acc[1] = fmaf(al, bf_hi(u.x), acc[1]);
            acc[2] = fmaf(al, bf_lo(u.y), acc[2]);
            acc[3] = fmaf(al, bf_hi(u.y), acc[3]);
            acc[4] = fmaf(al, bf_lo(u.z), acc[4]);
            acc[5] = fmaf(al, bf_hi(u.z), acc[5]);
            acc[6] = fmaf(al, bf_lo(u.w), acc[6]);
            acc[7] = fmaf(al, bf_hi(u.w), acc[7]);
        }
#pragma unroll
        for (int o = 8; o <= 32; o <<= 1) {
#pragma unroll
            for (int k = 0; k < 8; ++k) acc[k] += __shfl_xor(acc[k], o);
        }

        if (lane < 8) {   // lane == c; owns channels 8c..8c+7
            const float4 b0 = reinterpret_cast<const float4*>(bias)[2 * c];
            const float4 b1 = reinterpret_cast<const float4*>(bias)[2 * c + 1];
            float4 v0, v1;
            v0.x = acc[0] * inv + b0.x;
            v0.y = acc[1] * inv + b0.y;
            v0.z = acc[2] * inv + b0.z;
            v0.w = acc[3] * inv + b0.w;
            v1.x = acc[4] * inv + b1.x;
            v1.y = acc[5] * inv + b1.y;
            v1.z = acc[6] * inv + b1.z;
            v1.w = acc[7] * inv + b1.w;
            v0.x = v0.x > 0.0f ? v0.x : NEG_OUT * v0.x;
            v0.y = v0.y > 0.0f ? v0.y : NEG_OUT * v0.y;
            v0.z = v0.z > 0.0f ? v0.z : NEG_OUT * v0.z;
            v0.w = v0.w > 0.0f ? v0.w : NEG_OUT * v0.w;
            v1.x = v1.x > 0.0f ? v1.x : NEG_OUT * v1.x;
            v1.y = v1.y > 0.0f ? v1.y : NEG_OUT * v1.y;
            v1.z = v1.z > 0.0f ? v1.z : NEG_OUT * v1.z;
            v1.w = v1.w > 0.0f ? v1.w : NEG_OUT * v1.w;
            float4* orow = reinterpret_cast<float4*>(out + (long long)n * D);
            orow[2 * c]     = v0;
            orow[2 * c + 1] = v1;
        }
    } else {
        // fallback for deg > MAXD (statistically never; correctness-required)
        float mx = -1e30f;
        for (int j = lane; j < deg; j += 64) {
            int sn = perm[base + j];
            float lg = a_src[sn] + adn;
            lg = lg > 0.0f ? lg : NEG_GAT * lg;
            mx = fmaxf(mx, lg);
        }
#pragma unroll
        for (int o = 32; o >= 1; o >>= 1) mx = fmaxf(mx, __shfl_xor(mx, o));

        float se = 0.0f;
        for (int j = lane; j < deg; j += 64) {
            int sn = perm[base + j];
            float lg = a_src[sn] + adn;
            lg = lg > 0.0f ? lg : NEG_GAT * lg;
            se += __expf(lg - mx);
        }
#pragma unroll
        for (int o = 32; o >= 1; o >>= 1) se += __shfl_xor(se, o);
        const float inv = 1.0f / (se + 1e-16f);
        if (lane == 0) scale_slots[n] = inv * __expf(-mx);

        float acc = 0.0f;
        for (int j = 0; j < deg; ++j) {
            int sn = perm[base + j];
            float lg = a_src[sn] + adn;
            lg = lg > 0.0f ? lg : NEG_GAT * lg;
            float al = __expf(lg - mx) * inv;
            acc = fmaf(al, __bfloat162float(hb[(long long)sn * D + lane]), acc);
        }
        float v = acc + bias[lane];
        v = v > 0.0f ? v : NEG_OUT * v;
        out[(long long)n * D + lane] = v;
    }
}

// ---- alpha in edge order (coalesced writes) ----
__global__ void k_alphaE(const int* __restrict__ srcI, const int* __restrict__ dstI,
                         const float* __restrict__ a_src, const float* __restrict__ a_dst,
                         const float* __restrict__ scale_slots,
                         float* __restrict__ alpha_out, int E)
{
    int i = blockIdx.x * blockDim.x + threadIdx.x;
    if (i >= E) return;
    int sn = srcI[i], dn = dstI[i];
    float lg = a_src[sn] + a_dst[dn];
    lg = lg > 0.0f ? lg : NEG_GAT * lg;
    alpha_out[i] = __expf(lg) * scale_slots[dn];
}

// ---- self-loop alpha: overwrite parked scale with true alpha ----
__global__ void k_alphaS(const float* __restrict__ a_src, const float* __restrict__ a_dst,
                         float* __restrict__ scale_slots, int N)
{
    int n = blockIdx.x * blockDim.x + threadIdx.x;
    if (n >= N) return;
    float lg = a_src[n] + a_dst[n];
    lg = lg > 0.0f ? lg : NEG_GAT * lg;
    scale_slots[n] = __expf(lg) * scale_slots[n];
}

extern "C" void kernel_launch(void* const* d_in, const int* in_sizes, int n_in,
                              void* d_out, int out_size, void* d_ws, size_t ws_size,
                              hipStream_t stream)
{
    const int* x          = (const int*)d_in[0];
    const int* ei         = (const int*)d_in[1];
    const float* emb      = (const float*)d_in[2];
    const float* W        = (const float*)d_in[3];
    const float* att_src  = (const float*)d_in[4];
    const float* att_dst  = (const float*)d_in[5];
    const float* bias     = (const float*)d_in[6];

    const int N = in_sizes[0];
    const int E = in_sizes[1] / 2;
    const int* srcI = ei;       // edge_index[0]
    const int* dstI = ei + E;   // edge_index[1]
    const int NC = (N + CHUNK - 1) / CHUNK;

    char* p = (char*)d_ws;
    size_t off = 0;
    auto take = [&](size_t bytes) {
        char* q = p + off;
        off += (bytes + 15) & ~size_t(15);
        return q;
    };
    int* partial   = (int*)take((size_t)NC * 4);
    int* rp        = (int*)take((size_t)N * 4);
    float* a_src_b = (float*)take((size_t)N * 4);
    float* a_dst_b = (float*)take((size_t)N * 4);
    int* perm      = (int*)take((size_t)(E + N) * 4);
    bf16* hb       = (bf16*)take((size_t)N * D * 2);   // ~20.8 MB total (under proven 33.6)

    float* out         = (float*)d_out;
    float* alpha_out   = out + (long long)N * D;
    float* scale_slots = alpha_out + E;

    k_init  <<<(N + 255) / 256, 256, 0, stream>>>(rp, N);
    k_count <<<(E + 255) / 256, 256, 0, stream>>>(dstI, rp, E);
    k_node  <<<(N + 3) / 4, 256, 0, stream>>>(x, emb, W, att_src, att_dst,
                                              hb, a_src_b, a_dst_b, N);
    k_scan1 <<<NC, CHUNK, 0, stream>>>(rp, partial, N);
    k_scan2 <<<1, 512, 0, stream>>>(partial, NC);
    k_scan3 <<<NC, CHUNK, 0, stream>>>(rp, partial, N);
    k_place <<<(E + N + 255) / 256, 256, 0, stream>>>(srcI, dstI, rp, perm, E, N);
    k_agg   <<<(N + 3) / 4, 256, 0, stream>>>(rp, perm, a_src_b, a_dst_b,
                                              hb, bias, out, scale_slots, E, N);
    k_alphaE<<<(E + 255) / 256, 256, 0, stream>>>(srcI, dstI, a_src_b, a_dst_b,
                                                  scale_slots, alpha_out, E);
    k_alphaS<<<(N + 255) / 256, 256, 0, stream>>>(a_src_b, a_dst_b, scale_slots, N);
}